// Round 4
// baseline (507.421 us; speedup 1.0000x reference)
//
#include <hip/hip_runtime.h>

#define NUM_GRAPHS 64
#define NSC 160                 // sub-chunks; N = 100000 = 160 * 625
#define SCN 625                 // nodes per sub-chunk (10-bit local id)
#define SCF 1875                // floats per sub-chunk accumulator
#define SCFP 1888               // padded stride (mult of 4)
#define SB 512                  // bin blocks (2 blocks/CU)
#define DCAP 44032              // dense records per sub-chunk; mean 40000, +20 sigma
#define EBR 8                   // energy-bin replicas
#define EBP (NUM_GRAPHS + 1)    // padded row: replica r, graph g -> bank (r+g)%32
#define PBREC 12800             // per-block record buffer (2*6250 = 12500)

// ---------------------------------------------------------------------------
// P0: pack pos[N,3] + batch[N] -> pos4 = {x,y,z, bits(batch)}.
__global__ __launch_bounds__(256) void pack_kernel(
    const float* __restrict__ pos, const int* __restrict__ batch,
    float4* __restrict__ pos4, int N)
{
    const int n = blockIdx.x * 256 + threadIdx.x;
    if (n < N) {
        float4 v;
        v.x = pos[3 * n + 0];
        v.y = pos[3 * n + 1];
        v.z = pos[3 * n + 2];
        v.w = __int_as_float(batch[n]);
        pos4[n] = v;
    }
}

// ---------------------------------------------------------------------------
// P1: LDS counting-sort bin. Flush now APPENDS each bin's contiguous run to a
// dense per-s global stream via one global atomic cursor per s. Order within
// a stream is arbitrary (accumulation is atomic), so no metadata survives:
// the accumulate kernel needs only gcount[s]. Record: own_loc(10b) |
// other_global(17b)<<10 | eflag<<27.
__global__ __launch_bounds__(1024, 8) void bin_kernel(
    const int* __restrict__ ei,            // [2,E]
    unsigned int* __restrict__ dense,      // [NSC][DCAP]
    int* __restrict__ gcount,              // [NSC], pre-zeroed
    int E, int per_block)
{
    __shared__ unsigned int buf[PBREC];      // 50.0 KB
    __shared__ int hist[NSC];
    __shared__ int csr[NSC];
    __shared__ int cursor[NSC];
    __shared__ int scan_s[NSC];

    const int t = threadIdx.x, b = blockIdx.x;
    const int lane = t & 63, w = t >> 6;     // 16 waves
    const int e0 = b * per_block, e1 = min(E, e0 + per_block);

    for (int i = t; i < NSC; i += 1024) hist[i] = 0;
    __syncthreads();

    // pass 1: histogram (both endpoints)
    for (int e = e0 + t; e < e1; e += 1024) {
        const int iv = ei[e], jv = ei[E + e];
        atomicAdd(&hist[iv / SCN], 1);
        atomicAdd(&hist[jv / SCN], 1);
    }
    __syncthreads();

    // Hillis-Steele inclusive scan over 160 bins
    if (t < NSC) scan_s[t] = hist[t];
    __syncthreads();
    for (int d = 1; d < NSC; d <<= 1) {
        int v = 0;
        if (t < NSC && t >= d) v = scan_s[t - d];
        __syncthreads();
        if (t < NSC) scan_s[t] += v;
        __syncthreads();
    }
    if (t < NSC) {
        const int excl = scan_s[t] - hist[t];
        csr[t] = excl;
        cursor[t] = excl;
    }
    __syncthreads();

    // pass 2: scatter records into LDS at exact offsets
    for (int e = e0 + t; e < e1; e += 1024) {
        const int iv = ei[e], jv = ei[E + e];
        const int si = iv / SCN, sj = jv / SCN;
        const int s1 = atomicAdd(&cursor[si], 1);
        buf[s1] = (unsigned int)(iv - si * SCN) | ((unsigned int)jv << 10) | (1u << 27);
        const int s2 = atomicAdd(&cursor[sj], 1);
        buf[s2] = (unsigned int)(jv - sj * SCN) | ((unsigned int)iv << 10);
    }
    __syncthreads();

    // flush: wave per bin — reserve a dense-stream slot, copy the run.
    // Contiguous LDS reads, coalesced global writes.
    for (int s = w; s < NSC; s += 16) {
        const int base = csr[s];
        int cnt = hist[s];
        int gbase = 0;
        if (lane == 0) gbase = atomicAdd(&gcount[s], cnt);
        gbase = __shfl(gbase, 0);
        if (gbase + cnt > DCAP) cnt = max(0, DCAP - gbase);   // 20-sigma guard
        unsigned int* dst = dense + (size_t)s * DCAP + gbase;
        for (int k = lane; k < cnt; k += 64)
            dst[k] = buf[base + k];
    }
}

// ---------------------------------------------------------------------------
// P2: accumulate — search-free dense drain. Block (s,g) streams records
// [g*per, g*per+per) of sub-chunk s's dense array: perfectly sequential,
// coalesced, zero per-record metadata (R3 ablations showed the old
// boundary-search scaffolding, not the memory phases, was the cost).
template<int G>
__global__ __launch_bounds__(256, 8) void accumulate_kernel(
    const float4* __restrict__ pos4,
    const unsigned int* __restrict__ dense,
    const int* __restrict__ gcount,
    float* __restrict__ energy,        // d_out[0..63], pre-zeroed
    float* __restrict__ partials)      // [NSC*G][SCFP]
{
    __shared__ float4 slab[SCN];
    __shared__ __align__(16) float facc[SCFP];
    __shared__ float ebins[EBR][EBP];

    const int t    = threadIdx.x;
    const int lane = t & 63;
    const int s    = blockIdx.x % NSC;     // stride-160 -> same XCD (160%8==0)
    const int g    = blockIdx.x / NSC;

    for (int i = t; i < SCN; i += 256) slab[i] = pos4[s * SCN + i];
    for (int i = 4 * t; i < SCFP; i += 1024) {
        float4 z = {0.f, 0.f, 0.f, 0.f};
        *(float4*)&facc[i] = z;
    }
    for (int i = t; i < EBR * EBP; i += 256) ((float*)ebins)[i] = 0.f;
    __syncthreads();

    const int n   = min(gcount[s], DCAP);
    const int per = (n + G - 1) / G;
    const int lo  = g * per;
    const int hi  = min(n, lo + per);
    const unsigned int* dp = dense + (size_t)s * DCAP;

    for (int base = lo; base < hi; base += 1024) {
        unsigned int rec[4];
        bool  val[4];
        float4 pb[4];
        // phase 1: sequential coalesced record loads
        #pragma unroll
        for (int u = 0; u < 4; ++u) {
            const int r = base + (u << 8) + t;
            val[u] = r < hi;
            if (val[u]) rec[u] = dp[r];
        }
        // phase 2: divergent pos4 gathers (L2-resident)
        #pragma unroll
        for (int u = 0; u < 4; ++u)
            if (val[u]) pb[u] = pos4[(rec[u] >> 10) & 0x1FFFF];
        // phase 3: compute + LDS atomics
        #pragma unroll
        for (int u = 0; u < 4; ++u) {
            if (val[u]) {
                const int a = (int)(rec[u] & 1023);
                const float4 pa = slab[a];
                const float dx = pa.x - pb[u].x;
                const float dy = pa.y - pb[u].y;
                const float dz = pa.z - pb[u].z;
                const float d     = sqrtf(dx*dx + dy*dy + dz*dz);
                const float delta = d - 1.0f;                     // R0 = 1
                const float sc    = __fdividef(delta, d + 1e-20f); // K = 1
                const int l = a * 3;
                atomicAdd(&facc[l + 0], -sc * dx);
                atomicAdd(&facc[l + 1], -sc * dy);
                atomicAdd(&facc[l + 2], -sc * dz);
                if (rec[u] >> 27)                                 // energy once/edge
                    atomicAdd(&ebins[lane & (EBR - 1)][__float_as_int(pa.w)],
                              0.5f * delta * delta);
            }
        }
    }

    __syncthreads();
    float* dst = partials + (size_t)(s * G + g) * SCFP;
    for (int i = 4 * t; i < SCFP; i += 1024)
        *(float4*)(dst + i) = *(const float4*)&facc[i];
    if (t < NUM_GRAPHS) {
        float e = 0.f;
        #pragma unroll
        for (int rp = 0; rp < EBR; ++rp) e += ebins[rp][t];
        atomicAdd(&energy[t], e);
    }
}

// ---------------------------------------------------------------------------
// P3: forces[s*SCF + l] = sum over G group-partials. Coalesced.
template<int G>
__global__ __launch_bounds__(256) void reduce_kernel(
    const float* __restrict__ partials, float* __restrict__ forces)
{
    const int idx = blockIdx.x * 256 + threadIdx.x;   // over NSC*SCF = 300000
    if (idx >= NSC * SCF) return;
    const int s = idx / SCF, l = idx - s * SCF;
    float sum = 0.f;
    #pragma unroll
    for (int g = 0; g < G; ++g)
        sum += partials[(size_t)(s * G + g) * SCFP + l];
    forces[idx] = sum;
}

// ---------------------------------------------------------------------------
extern "C" void kernel_launch(void* const* d_in, const int* in_sizes, int n_in,
                              void* d_out, int out_size, void* d_ws, size_t ws_size,
                              hipStream_t stream) {
    const float* pos   = (const float*)d_in[0];
    const int*   ei    = (const int*)d_in[1];
    const int*   batch = (const int*)d_in[2];

    const int E = in_sizes[1] / 2;     // 3200000
    const int N = in_sizes[0] / 3;     // 100000 = NSC*SCN

    float* energy = (float*)d_out;
    float* forces = (float*)d_out + NUM_GRAPHS;

    const int per_block = (E + SB - 1) / SB;   // 6250; 2*per_block <= PBREC

    // ws layout: pos4 1.6 MB | dense 28.2 MB | gcount 1 KB | partials G*1.2 MB
    char* w = (char*)d_ws;
    float4* pos4 = (float4*)w;
    size_t off = (size_t)N * 16;
    unsigned int* dense = (unsigned int*)(w + off);
    off += (size_t)NSC * DCAP * 4;
    int* gcount = (int*)(w + off);
    off += 1024;
    float* partials = (float*)(w + off);

    // energy accumulates via atomics -> zero it; dense-stream cursors -> zero.
    hipMemsetAsync(d_out, 0, NUM_GRAPHS * sizeof(float), stream);
    hipMemsetAsync(gcount, 0, NSC * sizeof(int), stream);

    pack_kernel<<<(N + 255) / 256, 256, 0, stream>>>(pos, batch, pos4, N);

    bin_kernel<<<SB, 1024, 0, stream>>>(ei, dense, gcount, E, per_block);

    const size_t need16 = off + (size_t)NSC * 16 * SCFP * sizeof(float);
    if (ws_size >= need16) {
        accumulate_kernel<16><<<NSC * 16, 256, 0, stream>>>(
            pos4, dense, gcount, energy, partials);
        reduce_kernel<16><<<(NSC * SCF + 255) / 256, 256, 0, stream>>>(
            partials, forces);
    } else {
        accumulate_kernel<8><<<NSC * 8, 256, 0, stream>>>(
            pos4, dense, gcount, energy, partials);
        reduce_kernel<8><<<(NSC * SCF + 255) / 256, 256, 0, stream>>>(
            partials, forces);
    }
}

// Round 5
// 376.595 us; speedup vs baseline: 1.3474x; 1.3474x over previous
//
#include <hip/hip_runtime.h>

#define NUM_GRAPHS 64
#define NSC 160                 // sub-chunks; N = 100000 = 160 * 625
#define SCN 625                 // nodes per sub-chunk (10-bit local id)
#define SCF 1875                // floats per sub-chunk accumulator
#define SCFP 1888               // padded stride (mult of 4)
#define SB 512                  // bin blocks (2 blocks/CU)
#define DCAP 44032              // dense records per sub-chunk; mean 40000, +20 sigma
#define EBR 8                   // energy-bin replicas
#define EBP (NUM_GRAPHS + 1)    // padded row: replica r, graph g -> bank (r+g)%32
#define PBREC 12800             // per-block record buffer (2*6250 = 12500)

// ---------------------------------------------------------------------------
// P0: pack pos[N,3] + batch[N] -> pos4 = {x,y,z, bits(batch)}.
__global__ __launch_bounds__(256) void pack_kernel(
    const float* __restrict__ pos, const int* __restrict__ batch,
    float4* __restrict__ pos4, int N)
{
    const int n = blockIdx.x * 256 + threadIdx.x;
    if (n < N) {
        float4 v;
        v.x = pos[3 * n + 0];
        v.y = pos[3 * n + 1];
        v.z = pos[3 * n + 2];
        v.w = __int_as_float(batch[n]);
        pos4[n] = v;
    }
}

// ---------------------------------------------------------------------------
// P1: LDS counting-sort bin -> dense per-s global streams. R4's flush
// serialized on gcount atomics (512 blocks in lockstep on the same counter,
// 10 sequential round trips per wave -> 320 us). Fix: lanes 0-9 of each wave
// reserve all 10 of its bins' slots IN PARALLEL (one round trip), copy loop
// reads gbase/cnt via shfl. Record: own_loc(10b)|other(17b)<<10|eflag<<27.
__global__ __launch_bounds__(1024, 8) void bin_kernel(
    const int* __restrict__ ei,            // [2,E]
    unsigned int* __restrict__ dense,      // [NSC][DCAP]
    int* __restrict__ gcount,              // [NSC], pre-zeroed
    int E, int per_block)
{
    __shared__ unsigned int buf[PBREC];      // 50.0 KB
    __shared__ int hist[NSC];
    __shared__ int csr[NSC];
    __shared__ int cursor[NSC];
    __shared__ int scan_s[NSC];

    const int t = threadIdx.x, b = blockIdx.x;
    const int lane = t & 63, w = t >> 6;     // 16 waves
    const int e0 = b * per_block, e1 = min(E, e0 + per_block);

    for (int i = t; i < NSC; i += 1024) hist[i] = 0;
    __syncthreads();

    // pass 1: histogram (both endpoints)
    for (int e = e0 + t; e < e1; e += 1024) {
        const int iv = ei[e], jv = ei[E + e];
        atomicAdd(&hist[iv / SCN], 1);
        atomicAdd(&hist[jv / SCN], 1);
    }
    __syncthreads();

    // Hillis-Steele inclusive scan over 160 bins
    if (t < NSC) scan_s[t] = hist[t];
    __syncthreads();
    for (int d = 1; d < NSC; d <<= 1) {
        int v = 0;
        if (t < NSC && t >= d) v = scan_s[t - d];
        __syncthreads();
        if (t < NSC) scan_s[t] += v;
        __syncthreads();
    }
    if (t < NSC) {
        const int excl = scan_s[t] - hist[t];
        csr[t] = excl;
        cursor[t] = excl;
    }
    __syncthreads();

    // pass 2: scatter records into LDS at exact offsets
    for (int e = e0 + t; e < e1; e += 1024) {
        const int iv = ei[e], jv = ei[E + e];
        const int si = iv / SCN, sj = jv / SCN;
        const int s1 = atomicAdd(&cursor[si], 1);
        buf[s1] = (unsigned int)(iv - si * SCN) | ((unsigned int)jv << 10) | (1u << 27);
        const int s2 = atomicAdd(&cursor[sj], 1);
        buf[s2] = (unsigned int)(jv - sj * SCN) | ((unsigned int)iv << 10);
    }
    __syncthreads();

    // flush: wave owns bins {w, w+16, ..., w+144}. Lanes 0-9 reserve all 10
    // dense-stream slots in one parallel atomic burst; then 10 coalesced
    // run copies (contiguous LDS reads, coalesced global writes).
    {
        int myCnt = 0, myGb = 0;
        if (lane < 10) {
            const int sL = w + 16 * lane;
            myCnt = hist[sL];
            myGb  = atomicAdd(&gcount[sL], myCnt);
        }
        #pragma unroll
        for (int i = 0; i < 10; ++i) {
            const int s    = w + 16 * i;
            const int base = csr[s];
            int cnt        = __shfl(myCnt, i);
            const int gb   = __shfl(myGb,  i);
            if (gb + cnt > DCAP) cnt = max(0, DCAP - gb);   // 20-sigma guard
            unsigned int* dst = dense + (size_t)s * DCAP + gb;
            for (int k = lane; k < cnt; k += 64)
                dst[k] = buf[base + k];
        }
    }
}

// ---------------------------------------------------------------------------
// P2: accumulate — search-free dense drain (unchanged from R4 for a clean
// first measurement now that bin is fixed). Block (s,g) streams records
// [g*per, g*per+per) of sub-chunk s's dense array: sequential, coalesced,
// zero per-record metadata.
template<int G>
__global__ __launch_bounds__(256, 8) void accumulate_kernel(
    const float4* __restrict__ pos4,
    const unsigned int* __restrict__ dense,
    const int* __restrict__ gcount,
    float* __restrict__ energy,        // d_out[0..63], pre-zeroed
    float* __restrict__ partials)      // [NSC*G][SCFP]
{
    __shared__ float4 slab[SCN];
    __shared__ __align__(16) float facc[SCFP];
    __shared__ float ebins[EBR][EBP];

    const int t    = threadIdx.x;
    const int lane = t & 63;
    const int s    = blockIdx.x % NSC;     // stride-160 -> same XCD (160%8==0)
    const int g    = blockIdx.x / NSC;

    for (int i = t; i < SCN; i += 256) slab[i] = pos4[s * SCN + i];
    for (int i = 4 * t; i < SCFP; i += 1024) {
        float4 z = {0.f, 0.f, 0.f, 0.f};
        *(float4*)&facc[i] = z;
    }
    for (int i = t; i < EBR * EBP; i += 256) ((float*)ebins)[i] = 0.f;
    __syncthreads();

    const int n   = min(gcount[s], DCAP);
    const int per = (n + G - 1) / G;
    const int lo  = g * per;
    const int hi  = min(n, lo + per);
    const unsigned int* dp = dense + (size_t)s * DCAP;

    for (int base = lo; base < hi; base += 1024) {
        unsigned int rec[4];
        bool  val[4];
        float4 pb[4];
        // phase 1: sequential coalesced record loads
        #pragma unroll
        for (int u = 0; u < 4; ++u) {
            const int r = base + (u << 8) + t;
            val[u] = r < hi;
            if (val[u]) rec[u] = dp[r];
        }
        // phase 2: divergent pos4 gathers (L2-resident)
        #pragma unroll
        for (int u = 0; u < 4; ++u)
            if (val[u]) pb[u] = pos4[(rec[u] >> 10) & 0x1FFFF];
        // phase 3: compute + LDS atomics
        #pragma unroll
        for (int u = 0; u < 4; ++u) {
            if (val[u]) {
                const int a = (int)(rec[u] & 1023);
                const float4 pa = slab[a];
                const float dx = pa.x - pb[u].x;
                const float dy = pa.y - pb[u].y;
                const float dz = pa.z - pb[u].z;
                const float d     = sqrtf(dx*dx + dy*dy + dz*dz);
                const float delta = d - 1.0f;                      // R0 = 1
                const float sc    = __fdividef(delta, d + 1e-20f); // K = 1
                const int l = a * 3;
                atomicAdd(&facc[l + 0], -sc * dx);
                atomicAdd(&facc[l + 1], -sc * dy);
                atomicAdd(&facc[l + 2], -sc * dz);
                if (rec[u] >> 27)                                  // energy once/edge
                    atomicAdd(&ebins[lane & (EBR - 1)][__float_as_int(pa.w)],
                              0.5f * delta * delta);
            }
        }
    }

    __syncthreads();
    float* dst = partials + (size_t)(s * G + g) * SCFP;
    for (int i = 4 * t; i < SCFP; i += 1024)
        *(float4*)(dst + i) = *(const float4*)&facc[i];
    if (t < NUM_GRAPHS) {
        float e = 0.f;
        #pragma unroll
        for (int rp = 0; rp < EBR; ++rp) e += ebins[rp][t];
        atomicAdd(&energy[t], e);
    }
}

// ---------------------------------------------------------------------------
// P3: forces[s*SCF + l] = sum over G group-partials. Coalesced.
template<int G>
__global__ __launch_bounds__(256) void reduce_kernel(
    const float* __restrict__ partials, float* __restrict__ forces)
{
    const int idx = blockIdx.x * 256 + threadIdx.x;   // over NSC*SCF = 300000
    if (idx >= NSC * SCF) return;
    const int s = idx / SCF, l = idx - s * SCF;
    float sum = 0.f;
    #pragma unroll
    for (int g = 0; g < G; ++g)
        sum += partials[(size_t)(s * G + g) * SCFP + l];
    forces[idx] = sum;
}

// ---------------------------------------------------------------------------
extern "C" void kernel_launch(void* const* d_in, const int* in_sizes, int n_in,
                              void* d_out, int out_size, void* d_ws, size_t ws_size,
                              hipStream_t stream) {
    const float* pos   = (const float*)d_in[0];
    const int*   ei    = (const int*)d_in[1];
    const int*   batch = (const int*)d_in[2];

    const int E = in_sizes[1] / 2;     // 3200000
    const int N = in_sizes[0] / 3;     // 100000 = NSC*SCN

    float* energy = (float*)d_out;
    float* forces = (float*)d_out + NUM_GRAPHS;

    const int per_block = (E + SB - 1) / SB;   // 6250; 2*per_block <= PBREC

    // ws layout: pos4 1.6 MB | dense 28.2 MB | gcount 1 KB | partials G*1.2 MB
    char* w = (char*)d_ws;
    float4* pos4 = (float4*)w;
    size_t off = (size_t)N * 16;
    unsigned int* dense = (unsigned int*)(w + off);
    off += (size_t)NSC * DCAP * 4;
    int* gcount = (int*)(w + off);
    off += 1024;
    float* partials = (float*)(w + off);

    // energy accumulates via atomics -> zero it; dense-stream cursors -> zero.
    hipMemsetAsync(d_out, 0, NUM_GRAPHS * sizeof(float), stream);
    hipMemsetAsync(gcount, 0, NSC * sizeof(int), stream);

    pack_kernel<<<(N + 255) / 256, 256, 0, stream>>>(pos, batch, pos4, N);

    bin_kernel<<<SB, 1024, 0, stream>>>(ei, dense, gcount, E, per_block);

    const size_t need16 = off + (size_t)NSC * 16 * SCFP * sizeof(float);
    if (ws_size >= need16) {
        accumulate_kernel<16><<<NSC * 16, 256, 0, stream>>>(
            pos4, dense, gcount, energy, partials);
        reduce_kernel<16><<<(NSC * SCF + 255) / 256, 256, 0, stream>>>(
            partials, forces);
    } else {
        accumulate_kernel<8><<<NSC * 8, 256, 0, stream>>>(
            pos4, dense, gcount, energy, partials);
        reduce_kernel<8><<<(NSC * SCF + 255) / 256, 256, 0, stream>>>(
            partials, forces);
    }
}

// Round 6
// 205.096 us; speedup vs baseline: 2.4741x; 1.8362x over previous
//
#include <hip/hip_runtime.h>

#define NUM_GRAPHS 64
#define NSC 160                 // sub-chunks; N = 100000 = 160 * 625
#define SCN 625                 // nodes per sub-chunk (10-bit local id)
#define SCF 1875                // floats per sub-chunk accumulator
#define SCFP 1888               // padded stride (mult of 4)
#define SB 512                  // bin blocks (2 blocks/CU)
#define CAP 128                 // records per (bin-block, sub-chunk); mean 78, +5.7 sigma
#define SEGSTRIDE (NSC * CAP)   // record-region stride per segment
#define PBREC 12800             // per-block record buffer (2*6250 = 12500)

// ---------------------------------------------------------------------------
// P0: pack pos[N,3] + batch[N] -> pos4 = {x,y,z, bits(batch)}.
__global__ __launch_bounds__(256) void pack_kernel(
    const float* __restrict__ pos, const int* __restrict__ batch,
    float4* __restrict__ pos4, int N)
{
    const int n = blockIdx.x * 256 + threadIdx.x;
    if (n < N) {
        float4 v;
        v.x = pos[3 * n + 0];
        v.y = pos[3 * n + 1];
        v.z = pos[3 * n + 2];
        v.w = __int_as_float(batch[n]);
        pos4[n] = v;
    }
}

// ---------------------------------------------------------------------------
// P1: LDS counting-sort bin, LUT-FREE flush — exact R0/R2 proven version
// (recs/counts layout; the dense-stream global-atomic flush of R4/R5 was a
// 2x regression and is reverted). Record: own_loc(10b)|other(17b)<<10|ef<<27.
__global__ __launch_bounds__(1024, 8) void bin_kernel(
    const int* __restrict__ ei,            // [2,E]
    unsigned int* __restrict__ recs,       // [SB][NSC][CAP]
    int* __restrict__ counts,              // [SB][NSC]
    int E, int per_block)
{
    __shared__ unsigned int buf[PBREC];      // 50.0 KB
    __shared__ int hist[NSC];
    __shared__ int csr[NSC];
    __shared__ int cursor[NSC];
    __shared__ int scan_s[NSC];

    const int t = threadIdx.x, b = blockIdx.x;
    const int lane = t & 63, w = t >> 6;     // 16 waves
    const int e0 = b * per_block, e1 = min(E, e0 + per_block);

    for (int i = t; i < NSC; i += 1024) hist[i] = 0;
    __syncthreads();

    // pass 1: histogram (both endpoints)
    for (int e = e0 + t; e < e1; e += 1024) {
        const int iv = ei[e], jv = ei[E + e];
        atomicAdd(&hist[iv / SCN], 1);
        atomicAdd(&hist[jv / SCN], 1);
    }
    __syncthreads();

    // Hillis-Steele inclusive scan over 160 bins
    if (t < NSC) scan_s[t] = hist[t];
    __syncthreads();
    for (int d = 1; d < NSC; d <<= 1) {
        int v = 0;
        if (t < NSC && t >= d) v = scan_s[t - d];
        __syncthreads();
        if (t < NSC) scan_s[t] += v;
        __syncthreads();
    }
    if (t < NSC) {
        const int excl = scan_s[t] - hist[t];
        csr[t] = excl;
        cursor[t] = excl;
    }
    __syncthreads();

    // pass 2: scatter records into LDS at exact offsets (no lut!)
    for (int e = e0 + t; e < e1; e += 1024) {
        const int iv = ei[e], jv = ei[E + e];
        const int si = iv / SCN, sj = jv / SCN;
        const int s1 = atomicAdd(&cursor[si], 1);
        buf[s1] = (unsigned int)(iv - si * SCN) | ((unsigned int)jv << 10) | (1u << 27);
        const int s2 = atomicAdd(&cursor[sj], 1);
        buf[s2] = (unsigned int)(jv - sj * SCN) | ((unsigned int)iv << 10);
    }
    __syncthreads();

    // flush: wave per bin — contiguous LDS reads, coalesced global writes
    unsigned int* dst0 = recs + (size_t)b * NSC * CAP;
    for (int s = w; s < NSC; s += 16) {
        const int base = csr[s];
        const int cnt  = min(hist[s], CAP);
        for (int k = lane; k < cnt; k += 64)
            dst0[s * CAP + k] = buf[base + k];
        if (lane == 0) counts[b * NSC + s] = cnt;
    }
}

// ---------------------------------------------------------------------------
// P2: accumulate — R2's proven boundary-search drain, with two changes:
//  (a) facc adds via __hip_atomic_fetch_add(workgroup, relaxed) to force
//      native ds_add_f32 lowering (theory: plain atomicAdd(float*) on LDS
//      emits a CAS retry loop = the invariant 136us serializer).
//  (b) energy in registers: batch is sorted, so a 625-node chunk spans at
//      most 2 graph ids {slab[0].w, slab[624].w} (graphs ~1560+-39 nodes
//      >> 625). Removes all 3.2M ebins LDS atomics + the replica array.
template<int G>
__global__ __launch_bounds__(256, 8) void accumulate_kernel(
    const float4* __restrict__ pos4,
    const unsigned int* __restrict__ recs,
    const int* __restrict__ counts,
    float* __restrict__ energy,        // d_out[0..63], pre-zeroed
    float* __restrict__ partials)      // [NSC*G][SCFP]
{
    __shared__ float4 slab[SCN];
    __shared__ __align__(16) float facc[SCFP];
    __shared__ float ered[8];              // 4 waves x {e0,e1}

    const int t    = threadIdx.x;
    const int lane = t & 63;
    const int w    = t >> 6;               // 4 waves
    const int s    = blockIdx.x % NSC;     // stride-160 -> same XCD (160%8==0)
    const int g    = blockIdx.x / NSC;

    constexpr int SPB   = SB / G;          // segments per block: 64 / 32
    constexpr int SPW   = SPB / 4;         // segments per wave:  16 / 8
    constexpr int NPASS = (SPW + 7) / 8;   // 8-segment passes:    2 / 1

    for (int i = t; i < SCN; i += 256) slab[i] = pos4[s * SCN + i];
    for (int i = 4 * t; i < SCFP; i += 1024) {
        float4 z = {0.f, 0.f, 0.f, 0.f};
        *(float4*)&facc[i] = z;
    }
    __syncthreads();

    const int gmin_i = __float_as_int(slab[0].w);
    float e_lo = 0.f, e_hi = 0.f;          // energy for gmin / gmax

    for (int pass = 0; pass < NPASS; ++pass) {
        const int seg0 = g * SPB + w * SPW + pass * 8;
        int v = (lane < 8) ? counts[(seg0 + lane) * NSC + s] : 0;
        #pragma unroll
        for (int d = 1; d < 8; d <<= 1) {
            const int u = __shfl_up(v, d);
            if (lane >= d) v += u;
        }
        const int b0 = __shfl(v, 0), b1 = __shfl(v, 1), b2 = __shfl(v, 2),
                  b3 = __shfl(v, 3), b4 = __shfl(v, 4), b5 = __shfl(v, 5),
                  b6 = __shfl(v, 6);
        const int tot = __shfl(v, 7);
        const unsigned int* bp = recs + ((size_t)seg0 * NSC + s) * CAP;

        for (int base = 0; base < tot; base += 256) {
            unsigned int rec[4];
            bool  val[4];
            int   a[4];
            float4 pb[4];
            // phase 1: record loads (coalesced within runs)
            #pragma unroll
            for (int u = 0; u < 4; ++u) {
                const int r = base + lane + (u << 6);
                val[u] = r < tot;
                if (val[u]) {
                    const int k = (r >= b0) + (r >= b1) + (r >= b2) + (r >= b3)
                                + (r >= b4) + (r >= b5) + (r >= b6);
                    int prev = 0;
                    prev = (k > 0) ? b0 : prev; prev = (k > 1) ? b1 : prev;
                    prev = (k > 2) ? b2 : prev; prev = (k > 3) ? b3 : prev;
                    prev = (k > 4) ? b4 : prev; prev = (k > 5) ? b5 : prev;
                    prev = (k > 6) ? b6 : prev;
                    rec[u] = bp[(size_t)k * SEGSTRIDE + (r - prev)];
                }
            }
            // phase 2: divergent pos4 gathers (L2-resident)
            #pragma unroll
            for (int u = 0; u < 4; ++u) {
                if (val[u]) {
                    a[u]  = (int)(rec[u] & 1023);
                    pb[u] = pos4[(rec[u] >> 10) & 0x1FFFF];
                }
            }
            // phase 3: compute + native LDS float atomics + register energy
            #pragma unroll
            for (int u = 0; u < 4; ++u) {
                if (val[u]) {
                    const float4 pa = slab[a[u]];
                    const float dx = pa.x - pb[u].x;
                    const float dy = pa.y - pb[u].y;
                    const float dz = pa.z - pb[u].z;
                    const float d     = sqrtf(dx*dx + dy*dy + dz*dz);
                    const float delta = d - 1.0f;                 // R0 = 1
                    const float sc    = delta / (d + 1e-20f);     // K = 1
                    const int l = a[u] * 3;
                    __hip_atomic_fetch_add(&facc[l + 0], -sc * dx,
                        __ATOMIC_RELAXED, __HIP_MEMORY_SCOPE_WORKGROUP);
                    __hip_atomic_fetch_add(&facc[l + 1], -sc * dy,
                        __ATOMIC_RELAXED, __HIP_MEMORY_SCOPE_WORKGROUP);
                    __hip_atomic_fetch_add(&facc[l + 2], -sc * dz,
                        __ATOMIC_RELAXED, __HIP_MEMORY_SCOPE_WORKGROUP);
                    if (rec[u] >> 27) {                           // energy once/edge
                        const float e = 0.5f * delta * delta;
                        if (__float_as_int(pa.w) == gmin_i) e_lo += e;
                        else                                e_hi += e;
                    }
                }
            }
        }
    }

    // block-reduce the two energy registers; 2 global atomics per block
    #pragma unroll
    for (int d = 32; d > 0; d >>= 1) {
        e_lo += __shfl_down(e_lo, d);
        e_hi += __shfl_down(e_hi, d);
    }
    if (lane == 0) { ered[2 * w] = e_lo; ered[2 * w + 1] = e_hi; }

    __syncthreads();
    float* dst = partials + (size_t)(s * G + g) * SCFP;
    for (int i = 4 * t; i < SCFP; i += 1024)
        *(float4*)(dst + i) = *(const float4*)&facc[i];
    if (t == 0)
        atomicAdd(&energy[__float_as_int(slab[0].w)],
                  ered[0] + ered[2] + ered[4] + ered[6]);
    if (t == 1)
        atomicAdd(&energy[__float_as_int(slab[SCN - 1].w)],
                  ered[1] + ered[3] + ered[5] + ered[7]);
}

// ---------------------------------------------------------------------------
// P3: forces[s*SCF + l] = sum over G group-partials. Coalesced.
template<int G>
__global__ __launch_bounds__(256) void reduce_kernel(
    const float* __restrict__ partials, float* __restrict__ forces)
{
    const int idx = blockIdx.x * 256 + threadIdx.x;   // over NSC*SCF = 300000
    if (idx >= NSC * SCF) return;
    const int s = idx / SCF, l = idx - s * SCF;
    float sum = 0.f;
    #pragma unroll
    for (int g = 0; g < G; ++g)
        sum += partials[(size_t)(s * G + g) * SCFP + l];
    forces[idx] = sum;
}

// ---------------------------------------------------------------------------
extern "C" void kernel_launch(void* const* d_in, const int* in_sizes, int n_in,
                              void* d_out, int out_size, void* d_ws, size_t ws_size,
                              hipStream_t stream) {
    const float* pos   = (const float*)d_in[0];
    const int*   ei    = (const int*)d_in[1];
    const int*   batch = (const int*)d_in[2];

    const int E = in_sizes[1] / 2;     // 3200000
    const int N = in_sizes[0] / 3;     // 100000 = NSC*SCN

    float* energy = (float*)d_out;
    float* forces = (float*)d_out + NUM_GRAPHS;

    const int per_block = (E + SB - 1) / SB;   // 6250; 2*per_block <= PBREC

    // ws layout: pos4 1.6 MB | recs 41.9 MB | counts 327 KB | partials G*1.2 MB
    char* w = (char*)d_ws;
    float4* pos4 = (float4*)w;
    size_t off = (size_t)N * 16;
    unsigned int* recs = (unsigned int*)(w + off);
    off += (size_t)SB * NSC * CAP * 4;
    int* counts = (int*)(w + off);
    off += (size_t)SB * NSC * 4;
    float* partials = (float*)(w + off);

    // energy accumulates via atomics -> zero it; forces fully overwritten.
    hipMemsetAsync(d_out, 0, NUM_GRAPHS * sizeof(float), stream);

    pack_kernel<<<(N + 255) / 256, 256, 0, stream>>>(pos, batch, pos4, N);

    bin_kernel<<<SB, 1024, 0, stream>>>(ei, recs, counts, E, per_block);

    const size_t need16 = off + (size_t)NSC * 16 * SCFP * sizeof(float);
    if (ws_size >= need16) {
        accumulate_kernel<16><<<NSC * 16, 256, 0, stream>>>(
            pos4, recs, counts, energy, partials);
        reduce_kernel<16><<<(NSC * SCF + 255) / 256, 256, 0, stream>>>(
            partials, forces);
    } else {
        accumulate_kernel<8><<<NSC * 8, 256, 0, stream>>>(
            pos4, recs, counts, energy, partials);
        reduce_kernel<8><<<(NSC * SCF + 255) / 256, 256, 0, stream>>>(
            partials, forces);
    }
}